// Round 6
// baseline (867.185 us; speedup 1.0000x reference)
//
#include <hip/hip_runtime.h>
#include <hip/hip_bf16.h>
#include <stdint.h>

typedef __bf16 bf16;
typedef bf16 bf16x8 __attribute__((ext_vector_type(8)));
typedef bf16 bf16x4 __attribute__((ext_vector_type(4)));
typedef float f32x4 __attribute__((ext_vector_type(4)));

#define MFMA16(a, b, c) __builtin_amdgcn_mfma_f32_16x16x32_bf16((a), (b), (c), 0, 0, 0)

// async 16B global->LDS (wave-uniform LDS base, per-lane global src)
__device__ __forceinline__ void async_ld16(bf16* lds, const bf16* g) {
    __builtin_amdgcn_global_load_lds(
        (const __attribute__((address_space(1))) void*)g,
        (__attribute__((address_space(3))) void*)lds, 16, 0, 0);
}

// ---------------------------------------------------------------------------
// Kernel 1: QKV projection.  C[M,N] = X[M,K] * W[N,K]^T  (x @ W.T), bf16 out.
// z = 0 -> Q (row-major), z = 1 -> K (row-major), z = 2 -> V transposed
// (Vt[b][e][s]) so the attention kernel's PV B-fragments are contiguous.
// ---------------------------------------------------------------------------
__global__ __launch_bounds__(256) void proj_kernel(
    const float* __restrict__ X,
    const float* __restrict__ Wq,
    const float* __restrict__ Wk,
    const float* __restrict__ Wv,
    bf16* __restrict__ Qo,
    bf16* __restrict__ Ko,
    bf16* __restrict__ Vt)
{
    __shared__ bf16 As[128][72];
    __shared__ bf16 Bs[128][72];

    const int z    = blockIdx.z;
    const float* W = (z == 0) ? Wq : (z == 1) ? Wk : Wv;
    const int row0 = blockIdx.x * 128;
    const int col0 = blockIdx.y * 128;

    const int t    = threadIdx.x;
    const int w    = t >> 6;
    const int lane = t & 63;
    const int lg   = lane >> 4;
    const int lc   = lane & 15;
    const int wr   = (w >> 1) * 64;
    const int wc   = (w & 1) * 64;

    const int srow = t >> 1;
    const int sd0  = (t & 1) * 16;

    f32x4 acc[4][4];
    for (int a = 0; a < 4; ++a)
        for (int b = 0; b < 4; ++b)
            acc[a][b] = (f32x4){0.f, 0.f, 0.f, 0.f};

    for (int kt = 0; kt < 16; ++kt) {
        const int k = kt * 32;
        __syncthreads();
        {
            const float* xs = X + (size_t)(row0 + srow) * 512 + k + sd0;
            float4 a0 = *(const float4*)(xs + 0);
            float4 a1 = *(const float4*)(xs + 4);
            float4 a2 = *(const float4*)(xs + 8);
            float4 a3 = *(const float4*)(xs + 12);
            bf16x8 h0 = { (bf16)a0.x, (bf16)a0.y, (bf16)a0.z, (bf16)a0.w,
                          (bf16)a1.x, (bf16)a1.y, (bf16)a1.z, (bf16)a1.w };
            bf16x8 h1 = { (bf16)a2.x, (bf16)a2.y, (bf16)a2.z, (bf16)a2.w,
                          (bf16)a3.x, (bf16)a3.y, (bf16)a3.z, (bf16)a3.w };
            *(bf16x8*)&As[srow][sd0]     = h0;
            *(bf16x8*)&As[srow][sd0 + 8] = h1;

            const float* ws_ = W + (size_t)(col0 + srow) * 512 + k + sd0;
            float4 b0 = *(const float4*)(ws_ + 0);
            float4 b1 = *(const float4*)(ws_ + 4);
            float4 b2 = *(const float4*)(ws_ + 8);
            float4 b3 = *(const float4*)(ws_ + 12);
            bf16x8 g0 = { (bf16)b0.x, (bf16)b0.y, (bf16)b0.z, (bf16)b0.w,
                          (bf16)b1.x, (bf16)b1.y, (bf16)b1.z, (bf16)b1.w };
            bf16x8 g1 = { (bf16)b2.x, (bf16)b2.y, (bf16)b2.z, (bf16)b2.w,
                          (bf16)b3.x, (bf16)b3.y, (bf16)b3.z, (bf16)b3.w };
            *(bf16x8*)&Bs[srow][sd0]     = g0;
            *(bf16x8*)&Bs[srow][sd0 + 8] = g1;
        }
        __syncthreads();

        bf16x8 af[4], bfr[4];
        for (int fr = 0; fr < 4; ++fr)
            af[fr] = *(const bf16x8*)&As[wr + fr * 16 + lc][lg * 8];
        for (int fc = 0; fc < 4; ++fc)
            bfr[fc] = *(const bf16x8*)&Bs[wc + fc * 16 + lc][lg * 8];
        for (int fr = 0; fr < 4; ++fr)
            for (int fc = 0; fc < 4; ++fc)
                acc[fr][fc] = MFMA16(af[fr], bfr[fc], acc[fr][fc]);
    }

    if (z < 2) {
        bf16* outp = (z == 0) ? Qo : Ko;
        for (int fr = 0; fr < 4; ++fr)
            for (int fc = 0; fc < 4; ++fc) {
                const int colg = col0 + wc + fc * 16 + lc;
                const int rowb = row0 + wr + fr * 16 + lg * 4;
                for (int i = 0; i < 4; ++i)
                    outp[(size_t)(rowb + i) * 512 + colg] = (bf16)acc[fr][fc][i];
            }
    } else {
        for (int fr = 0; fr < 4; ++fr)
            for (int fc = 0; fc < 4; ++fc) {
                const int e    = col0 + wc + fc * 16 + lc;
                const int rowb = row0 + wr + fr * 16 + lg * 4;
                const int bb   = rowb >> 12;
                const int sl   = rowb & 4095;
                bf16x4 v = { (bf16)acc[fr][fc][0], (bf16)acc[fr][fc][1],
                             (bf16)acc[fr][fc][2], (bf16)acc[fr][fc][3] };
                *(bf16x4*)&Vt[(((size_t)(bb * 512 + e)) << 12) + sl] = v;
            }
    }
}

// ---------------------------------------------------------------------------
// Kernel 2: flash attention, no-max softmax, 3-barrier single-K-buffer
// schedule, 2 blocks/CU (LDS 74 KB) and 4 waves/SIMD (VGPR cap 128).
// SPLIT=true: grid 512, each block does one KV-half (32 iters), writes
// UNNORMALIZED O (z=0 -> Out, z=1 -> O1 ws) + row sums l; combine kernel
// finishes.  SPLIT=false: grid 256, full KV range, normalizes in-kernel.
// Per iter: issue V(i) -> vmcnt(8) [K(i) landed] -> bar -> QK(LDS) -> bar
// [K buf free] -> issue K(i+1) async -> exp/P-write -> lgkmcnt(0) -> bar
// -> PV.  vmcnt never drains to 0 inside the loop.
// ---------------------------------------------------------------------------
template<bool SPLIT>
__global__ __launch_bounds__(512, 4) void flash_kernel(
    const bf16* __restrict__ Q,
    const bf16* __restrict__ K,
    const bf16* __restrict__ Vt,
    const float* __restrict__ temp,
    float* __restrict__ Out,
    float* __restrict__ O1,
    float* __restrict__ lsum)
{
    extern __shared__ char smem[];
    bf16* Kb = (bf16*)smem;                   // [64*512]  64 KiB (single buf)
    bf16* Pb = (bf16*)(smem + 64 * 512 * 2);  // [64*72]   9 KiB
    __shared__ float l_part[64][2];

    const int L = blockIdx.x;
    int b, q0, z;
    if (SPLIT) {
        // XCD = L&7: z = XCD parity, batch = bits[2:1]; per-XCD set = 4 MB.
        z  = L & 1;
        b  = (L >> 1) & 3;
        q0 = (L >> 3) << 6;
    } else {
        z  = 0;
        b  = (L & 7) >> 1;
        q0 = (((L & 1) << 5) + (L >> 3)) << 6;
    }
    const int NIT   = SPLIT ? 32 : 64;
    const int kvoff = SPLIT ? z * 2048 : 0;

    const int t    = threadIdx.x;          // 0..511
    const int w    = t >> 6;               // wave 0..7
    const int lane = t & 63;
    const int lg   = lane >> 4;
    const int lc   = lane & 15;
    const int qrb  = (w >> 1) * 16;        // this wave's S q-row block
    const int par  = w & 1;                // key-col parity

    const float scale2 = temp[0] * 0.04419417382415922f * 1.4426950408889634f;

    const bf16* kbase = K  + (size_t)(b * 4096 + kvoff) * 512;
    const bf16* vbase = Vt + (size_t)b * 512 * 4096 + kvoff;

    // prologue: stage K tile 0 (wave w stages rows w*8..w*8+7, swizzled src)
#pragma unroll
    for (int j = 0; j < 8; ++j) {
        const int r = w * 8 + j;                      // r&7 == j
        async_ld16(Kb + (size_t)r * 512,
                   kbase + (size_t)r * 512 + ((lane ^ j) << 3));
    }

    // Q fragments, register-resident for the whole kernel
    bf16x8 qf[16];
    {
        const bf16* qrow = Q + ((size_t)(b * 4096 + q0 + qrb + lc)) * 512 + lg * 8;
#pragma unroll
        for (int kt = 0; kt < 16; ++kt)
            qf[kt] = *(const bf16x8*)(qrow + kt * 32);
    }

    f32x4 acc[4][4];
    for (int a = 0; a < 4; ++a)
        for (int c = 0; c < 4; ++c)
            acc[a][c] = (f32x4){0.f, 0.f, 0.f, 0.f};
    float Lacc[4] = {0.f, 0.f, 0.f, 0.f};

    __syncthreads();   // full drain: K tile 0 + qf resident

    // read-side swizzle constants (row_local & 7 == lc & 7 for both K rows)
    const int r7  = lc & 7;
    const int xlo = (lg ^ (r7 & 3)) << 3;
    const int xb2 = (r7 & 4) << 3;

    for (int it = 0; it < NIT; ++it) {
        // ---- issue V loads for THIS tile (consumed in PV) ----
        const bf16* vb0 = vbase + (size_t)(w * 64 + lc) * 4096 + it * 64 + lg * 8;
        bf16x8 vv[8];
#pragma unroll
        for (int kk2 = 0; kk2 < 2; ++kk2)
#pragma unroll
            for (int fc = 0; fc < 4; ++fc)
                vv[kk2 * 4 + fc] =
                    *(const bf16x8*)(vb0 + (size_t)fc * 16 * 4096 + kk2 * 32);

        // ---- K(i) landed: outstanding = K(i)8 + V8 -> wait to 8 ----
        asm volatile("s_waitcnt vmcnt(8)" ::: "memory");
        __builtin_amdgcn_s_barrier();

        // ---- S = Q K^T from LDS (swizzled ds_read_b128) ----
        f32x4 s0 = (f32x4){0.f, 0.f, 0.f, 0.f};
        f32x4 s1 = (f32x4){0.f, 0.f, 0.f, 0.f};
        const bf16* kr0 = Kb + (size_t)(par * 32 + lc) * 512 + xlo;
        const bf16* kr1 = kr0 + (size_t)16 * 512;
#pragma unroll
        for (int kt = 0; kt < 16; ++kt) {
            const int off = (kt * 32) ^ xb2;
            bf16x8 k0 = *(const bf16x8*)(kr0 + off);
            bf16x8 k1 = *(const bf16x8*)(kr1 + off);
            s0 = MFMA16(qf[kt], k0, s0);
            s1 = MFMA16(qf[kt], k1, s1);
        }

        // ---- all waves done reading K buffer ----
        __builtin_amdgcn_s_barrier();

        // ---- issue K(i+1) prefetch into the (now free) single buffer ----
        {
            const int nxt = (it + 1) & (NIT - 1);   // last iter: discarded
            const bf16* knx = kbase + (size_t)nxt * 64 * 512;
#pragma unroll
            for (int j = 0; j < 8; ++j) {
                const int r = w * 8 + j;
                async_ld16(Kb + (size_t)r * 512,
                           knx + (size_t)r * 512 + ((lane ^ j) << 3));
            }
        }

        // ---- P = exp2(s*scale2) -> LDS, accumulate denominator ----
#pragma unroll
        for (int i = 0; i < 4; ++i) {
            const int row = qrb + lg * 4 + i;
            float p0 = __builtin_amdgcn_exp2f(s0[i] * scale2);
            float p1 = __builtin_amdgcn_exp2f(s1[i] * scale2);
            Pb[row * 72 + par * 32 + lc]      = (bf16)p0;
            Pb[row * 72 + par * 32 + 16 + lc] = (bf16)p1;
            Lacc[i] += p0 + p1;
        }

        // ---- P visible; K(i+1) still in flight (vmcnt untouched) ----
        asm volatile("s_waitcnt lgkmcnt(0)" ::: "memory");
        __builtin_amdgcn_s_barrier();

        // ---- O += P * V (V regs: compiler waits vmcnt(8), keeps K in flight)
#pragma unroll
        for (int kk2 = 0; kk2 < 2; ++kk2) {
            bf16x8 pa[4];
#pragma unroll
            for (int fr = 0; fr < 4; ++fr)
                pa[fr] = *(const bf16x8*)&Pb[(fr * 16 + lc) * 72 + kk2 * 32 + lg * 8];
#pragma unroll
            for (int fc = 0; fc < 4; ++fc)
#pragma unroll
                for (int fr = 0; fr < 4; ++fr)
                    acc[fr][fc] = MFMA16(pa[fr], vv[kk2 * 4 + fc], acc[fr][fc]);
        }
    }

    // ---- denominator partials across the 16 lc lanes ----
#pragma unroll
    for (int d = 1; d < 16; d <<= 1)
#pragma unroll
        for (int i = 0; i < 4; ++i)
            Lacc[i] += __shfl_xor(Lacc[i], d);
    if (lc == 0)
#pragma unroll
        for (int i = 0; i < 4; ++i)
            l_part[qrb + lg * 4 + i][par] = Lacc[i];
    __syncthreads();   // also drains the final (discarded) prefetch

    if (SPLIT) {
        // ---- store UNNORMALIZED partial O + row sums l ----
        float* Og = (z == 0) ? Out : O1;
        if (t < 64)
            lsum[(size_t)(z * 4 + b) * 4096 + q0 + t] =
                l_part[t][0] + l_part[t][1];
        for (int fr = 0; fr < 4; ++fr)
            for (int fc = 0; fc < 4; ++fc) {
                const size_t base =
                    ((size_t)(b * 4096 + q0 + fr * 16 + lg * 4)) * 512 +
                    w * 64 + fc * 16 + lc;
#pragma unroll
                for (int i = 0; i < 4; ++i)
                    Og[base + (size_t)i * 512] = acc[fr][fc][i];
            }
    } else {
        for (int fr = 0; fr < 4; ++fr) {
            float invl[4];
#pragma unroll
            for (int i = 0; i < 4; ++i) {
                const int row = fr * 16 + lg * 4 + i;
                invl[i] = 1.0f / (l_part[row][0] + l_part[row][1]);
            }
            for (int fc = 0; fc < 4; ++fc) {
                const size_t base =
                    ((size_t)(b * 4096 + q0 + fr * 16 + lg * 4)) * 512 +
                    w * 64 + fc * 16 + lc;
#pragma unroll
                for (int i = 0; i < 4; ++i)
                    Out[base + (size_t)i * 512] = acc[fr][fc][i] * invl[i];
            }
        }
    }
}

// ---------------------------------------------------------------------------
// Kernel 3: combine the two KV-half partials: Out = (O0 + O1)/(l0 + l1).
// One float4 per thread: 2.097M float4 = 8192 blocks x 256 threads.
// ---------------------------------------------------------------------------
__global__ __launch_bounds__(256) void combine_kernel(
    float* __restrict__ Out,
    const float* __restrict__ O1,
    const float* __restrict__ lsum)
{
    const int idx = blockIdx.x * 256 + threadIdx.x;   // float4 index
    const int row = idx >> 7;                          // 128 float4 per row
    float4 a = ((const float4*)Out)[idx];
    float4 c = ((const float4*)O1)[idx];
    const float inv = 1.0f / (lsum[row] + lsum[16384 + row]);
    float4 r;
    r.x = (a.x + c.x) * inv;
    r.y = (a.y + c.y) * inv;
    r.z = (a.z + c.z) * inv;
    r.w = (a.w + c.w) * inv;
    ((float4*)Out)[idx] = r;
}

// ---------------------------------------------------------------------------
extern "C" void kernel_launch(void* const* d_in, const int* in_sizes, int n_in,
                              void* d_out, int out_size, void* d_ws, size_t ws_size,
                              hipStream_t stream) {
    const float* X    = (const float*)d_in[0];
    const float* Wq   = (const float*)d_in[1];
    const float* Wk   = (const float*)d_in[2];
    const float* Wv   = (const float*)d_in[3];
    const float* temp = (const float*)d_in[4];
    float* Out = (float*)d_out;

    const size_t NE = (size_t)4 * 4096 * 512;   // 8.39M elements per tensor
    bf16* Qw = (bf16*)d_ws;
    bf16* Kw = Qw + NE;
    bf16* Vt = Kw + NE;                          // 50.3 MB
    float* O1   = (float*)(Vt + NE);             // +33.6 MB (split path)
    float* lsum = O1 + NE;                       // +128 KB

    proj_kernel<<<dim3(128, 4, 3), 256, 0, stream>>>(X, Wq, Wk, Wv, Qw, Kw, Vt);

    // dynamic LDS: K single buffer 64 KiB + P 9 KiB = 74752 B -> 2 blocks/CU
    const size_t smem_bytes = (size_t)64 * 512 * 2 + (size_t)64 * 72 * 2;
    const size_t ws_needed  = 3 * NE * 2 + NE * 4 + (size_t)2 * 4 * 4096 * 4;

    if (ws_size >= ws_needed) {
        flash_kernel<true><<<dim3(512), 512, smem_bytes, stream>>>(
            Qw, Kw, Vt, temp, Out, O1, lsum);
        combine_kernel<<<dim3(8192), 256, 0, stream>>>(Out, O1, lsum);
    } else {
        flash_kernel<false><<<dim3(256), 512, smem_bytes, stream>>>(
            Qw, Kw, Vt, temp, Out, nullptr, nullptr);
    }
}

// Round 7
// 288.173 us; speedup vs baseline: 3.0093x; 3.0093x over previous
//
#include <hip/hip_runtime.h>
#include <hip/hip_bf16.h>
#include <stdint.h>

typedef __bf16 bf16;
typedef bf16 bf16x8 __attribute__((ext_vector_type(8)));
typedef bf16 bf16x4 __attribute__((ext_vector_type(4)));
typedef float f32x4 __attribute__((ext_vector_type(4)));

#define MFMA16(a, b, c) __builtin_amdgcn_mfma_f32_16x16x32_bf16((a), (b), (c), 0, 0, 0)

// async 16B global->LDS (wave-uniform LDS base, per-lane global src)
__device__ __forceinline__ void async_ld16(bf16* lds, const bf16* g) {
    __builtin_amdgcn_global_load_lds(
        (const __attribute__((address_space(1))) void*)g,
        (__attribute__((address_space(3))) void*)lds, 16, 0, 0);
}

// ---------------------------------------------------------------------------
// Kernel 1: QKV projection.  C[M,N] = X[M,K] * W[N,K]^T  (x @ W.T), bf16 out.
// z = 0 -> Q (row-major), z = 1 -> K (row-major), z = 2 -> V transposed
// (Vt[b][e][s]) so the attention kernel's PV B-fragments are contiguous.
// ---------------------------------------------------------------------------
__global__ __launch_bounds__(256) void proj_kernel(
    const float* __restrict__ X,
    const float* __restrict__ Wq,
    const float* __restrict__ Wk,
    const float* __restrict__ Wv,
    bf16* __restrict__ Qo,
    bf16* __restrict__ Ko,
    bf16* __restrict__ Vt)
{
    __shared__ bf16 As[128][72];
    __shared__ bf16 Bs[128][72];

    const int z    = blockIdx.z;
    const float* W = (z == 0) ? Wq : (z == 1) ? Wk : Wv;
    const int row0 = blockIdx.x * 128;
    const int col0 = blockIdx.y * 128;

    const int t    = threadIdx.x;
    const int w    = t >> 6;
    const int lane = t & 63;
    const int lg   = lane >> 4;
    const int lc   = lane & 15;
    const int wr   = (w >> 1) * 64;
    const int wc   = (w & 1) * 64;

    const int srow = t >> 1;
    const int sd0  = (t & 1) * 16;

    f32x4 acc[4][4];
    for (int a = 0; a < 4; ++a)
        for (int b = 0; b < 4; ++b)
            acc[a][b] = (f32x4){0.f, 0.f, 0.f, 0.f};

    for (int kt = 0; kt < 16; ++kt) {
        const int k = kt * 32;
        __syncthreads();
        {
            const float* xs = X + (size_t)(row0 + srow) * 512 + k + sd0;
            float4 a0 = *(const float4*)(xs + 0);
            float4 a1 = *(const float4*)(xs + 4);
            float4 a2 = *(const float4*)(xs + 8);
            float4 a3 = *(const float4*)(xs + 12);
            bf16x8 h0 = { (bf16)a0.x, (bf16)a0.y, (bf16)a0.z, (bf16)a0.w,
                          (bf16)a1.x, (bf16)a1.y, (bf16)a1.z, (bf16)a1.w };
            bf16x8 h1 = { (bf16)a2.x, (bf16)a2.y, (bf16)a2.z, (bf16)a2.w,
                          (bf16)a3.x, (bf16)a3.y, (bf16)a3.z, (bf16)a3.w };
            *(bf16x8*)&As[srow][sd0]     = h0;
            *(bf16x8*)&As[srow][sd0 + 8] = h1;

            const float* ws_ = W + (size_t)(col0 + srow) * 512 + k + sd0;
            float4 b0 = *(const float4*)(ws_ + 0);
            float4 b1 = *(const float4*)(ws_ + 4);
            float4 b2 = *(const float4*)(ws_ + 8);
            float4 b3 = *(const float4*)(ws_ + 12);
            bf16x8 g0 = { (bf16)b0.x, (bf16)b0.y, (bf16)b0.z, (bf16)b0.w,
                          (bf16)b1.x, (bf16)b1.y, (bf16)b1.z, (bf16)b1.w };
            bf16x8 g1 = { (bf16)b2.x, (bf16)b2.y, (bf16)b2.z, (bf16)b2.w,
                          (bf16)b3.x, (bf16)b3.y, (bf16)b3.z, (bf16)b3.w };
            *(bf16x8*)&Bs[srow][sd0]     = g0;
            *(bf16x8*)&Bs[srow][sd0 + 8] = g1;
        }
        __syncthreads();

        bf16x8 af[4], bfr[4];
        for (int fr = 0; fr < 4; ++fr)
            af[fr] = *(const bf16x8*)&As[wr + fr * 16 + lc][lg * 8];
        for (int fc = 0; fc < 4; ++fc)
            bfr[fc] = *(const bf16x8*)&Bs[wc + fc * 16 + lc][lg * 8];
        for (int fr = 0; fr < 4; ++fr)
            for (int fc = 0; fc < 4; ++fc)
                acc[fr][fc] = MFMA16(af[fr], bfr[fc], acc[fr][fc]);
    }

    if (z < 2) {
        bf16* outp = (z == 0) ? Qo : Ko;
        for (int fr = 0; fr < 4; ++fr)
            for (int fc = 0; fc < 4; ++fc) {
                const int colg = col0 + wc + fc * 16 + lc;
                const int rowb = row0 + wr + fr * 16 + lg * 4;
                for (int i = 0; i < 4; ++i)
                    outp[(size_t)(rowb + i) * 512 + colg] = (bf16)acc[fr][fc][i];
            }
    } else {
        for (int fr = 0; fr < 4; ++fr)
            for (int fc = 0; fc < 4; ++fc) {
                const int e    = col0 + wc + fc * 16 + lc;
                const int rowb = row0 + wr + fr * 16 + lg * 4;
                const int bb   = rowb >> 12;
                const int sl   = rowb & 4095;
                bf16x4 v = { (bf16)acc[fr][fc][0], (bf16)acc[fr][fc][1],
                             (bf16)acc[fr][fc][2], (bf16)acc[fr][fc][3] };
                *(bf16x4*)&Vt[(((size_t)(bb * 512 + e)) << 12) + sl] = v;
            }
    }
}

// ---------------------------------------------------------------------------
// Kernel 2: flash attention, no-max softmax, PING-PONG pipeline:
// iter i computes QK(i) (K from LDS buf i&1) INTERLEAVED with PV(i-1)
// (P from P-buf (i-1)&1, V from registers loaded in iter i-1).  Then
// exp(i) -> P-buf (i&1), one counted barrier: s_waitcnt vmcnt(8)
// [= K(i+1) prefetch landed; V(i) may still fly] + lgkmcnt(0) + s_barrier.
// K prefetch gets a FULL iteration; vmcnt never drains to 0 in the loop.
// V registers double-buffered by compile-time parity (vvA/vvB).
// 8 waves, q-tile 64, KV-tile 64, 1 block/CU, LDS 146 KB.
// ---------------------------------------------------------------------------
__global__ __launch_bounds__(512) void flash_kernel(
    const bf16* __restrict__ Q,
    const bf16* __restrict__ K,
    const bf16* __restrict__ Vt,
    const float* __restrict__ temp,
    float* __restrict__ Out)
{
    extern __shared__ char smem[];
    bf16* Kb = (bf16*)smem;                       // [2][64*512]  128 KiB
    bf16* Pb = (bf16*)(smem + 2 * 64 * 512 * 2);  // [2][64*72]   18 KiB
    __shared__ float l_part[64][2];

    // XCD-aware decode (bijective): XCD = L&7, batch = bits[2:1],
    // q-index = (L&1)*32 + (L>>3).  Each batch's K/V pinned to 2 XCDs.
    const int L  = blockIdx.x;
    const int b  = (L & 7) >> 1;
    const int q0 = (((L & 1) << 5) + (L >> 3)) << 6;

    const int t    = threadIdx.x;          // 0..511
    const int w    = t >> 6;               // wave 0..7
    const int lane = t & 63;
    const int lg   = lane >> 4;
    const int lc   = lane & 15;
    const int qrb  = (w >> 1) * 16;        // this wave's S q-row block
    const int par  = w & 1;                // key-col parity

    const float scale2 = temp[0] * 0.04419417382415922f * 1.4426950408889634f;

    const bf16* kbase = K  + (size_t)b * 4096 * 512;
    const bf16* vbase = Vt + (size_t)b * 512 * 4096;

    // prologue: stage K tile 0 into buf 0 (wave w stages rows w*8..w*8+7)
#pragma unroll
    for (int j = 0; j < 8; ++j) {
        const int r = w * 8 + j;                      // r&7 == j
        async_ld16(Kb + (size_t)r * 512,
                   kbase + (size_t)r * 512 + ((lane ^ j) << 3));
    }

    // Q fragments, register-resident for the whole kernel
    bf16x8 qf[16];
    {
        const bf16* qrow = Q + ((size_t)(b * 4096 + q0 + qrb + lc)) * 512 + lg * 8;
#pragma unroll
        for (int kt = 0; kt < 16; ++kt)
            qf[kt] = *(const bf16x8*)(qrow + kt * 32);
    }

    f32x4 acc[4][4];
    for (int a = 0; a < 4; ++a)
        for (int c = 0; c < 4; ++c)
            acc[a][c] = (f32x4){0.f, 0.f, 0.f, 0.f};
    float Lacc[4] = {0.f, 0.f, 0.f, 0.f};

    bf16x8 vvA[8], vvB[8];

    __syncthreads();   // full drain: K tile 0 + qf resident

    // read-side swizzle constants (row_local & 7 == lc & 7 for both K rows)
    const int r7  = lc & 7;
    const int xlo = (lg ^ (r7 & 3)) << 3;
    const int xb2 = (r7 & 4) << 3;

    // ---- iteration body ----------------------------------------------------
    // KC    = IT & 1 (compile-time literal at each expansion)
    // vvLD  = register set receiving V(IT); vvPV = set holding V(IT-1)
    // DO_PV = include PV(IT-1); DO_PF = prefetch K(IT+1)
#define ITER_BODY(IT, KC, vvLD, vvPV, DO_PV, DO_PF)                            \
    {                                                                          \
        /* issue K(IT+1) prefetch into the other buffer */                     \
        if (DO_PF) {                                                           \
            bf16* Kn = Kb + (size_t)((KC) ^ 1) * 32768;                        \
            const bf16* knx = kbase + (size_t)((IT) + 1) * 64 * 512;           \
            _Pragma("unroll")                                                  \
            for (int j = 0; j < 8; ++j) {                                      \
                const int r = w * 8 + j;                                       \
                async_ld16(Kn + (size_t)r * 512,                               \
                           knx + (size_t)r * 512 + ((lane ^ j) << 3));         \
            }                                                                  \
        }                                                                      \
        /* issue V(IT) register loads (consumed next iter) */                  \
        {                                                                      \
            const bf16* vb0 = vbase + (size_t)(w * 64 + lc) * 4096             \
                              + (IT) * 64 + lg * 8;                            \
            _Pragma("unroll")                                                  \
            for (int kk2 = 0; kk2 < 2; ++kk2)                                  \
                _Pragma("unroll")                                              \
                for (int fc = 0; fc < 4; ++fc)                                 \
                    vvLD[kk2 * 4 + fc] = *(const bf16x8*)(                     \
                        vb0 + (size_t)fc * 16 * 4096 + kk2 * 32);              \
        }                                                                      \
        /* QK(IT) from Kb[KC]  interleaved with  PV(IT-1) from Pb[KC^1] */     \
        f32x4 s0 = (f32x4){0.f, 0.f, 0.f, 0.f};                                \
        f32x4 s1 = (f32x4){0.f, 0.f, 0.f, 0.f};                                \
        {                                                                      \
            const bf16* Kc  = Kb + (size_t)(KC) * 32768;                       \
            const bf16* Pp  = Pb + (size_t)((KC) ^ 1) * (64 * 72);             \
            const bf16* kr0 = Kc + (size_t)(par * 32 + lc) * 512 + xlo;        \
            const bf16* kr1 = kr0 + (size_t)16 * 512;                          \
            _Pragma("unroll")                                                  \
            for (int half = 0; half < 2; ++half) {                             \
                bf16x8 pa[4];                                                  \
                if (DO_PV) {                                                   \
                    _Pragma("unroll")                                          \
                    for (int fr = 0; fr < 4; ++fr)                             \
                        pa[fr] = *(const bf16x8*)&Pp[(fr * 16 + lc) * 72       \
                                                     + half * 32 + lg * 8];    \
                }                                                              \
                _Pragma("unroll")                                              \
                for (int kh = 0; kh < 8; ++kh) {                               \
                    const int kt  = half * 8 + kh;                             \
                    const int off = (kt * 32) ^ xb2;                           \
                    bf16x8 k0 = *(const bf16x8*)(kr0 + off);                   \
                    bf16x8 k1 = *(const bf16x8*)(kr1 + off);                   \
                    s0 = MFMA16(qf[kt], k0, s0);                               \
                    s1 = MFMA16(qf[kt], k1, s1);                               \
                    if (DO_PV) {                                               \
                        const int fc = kh >> 1;                                \
                        const int f0 = (kh & 1) * 2;                           \
                        acc[f0][fc]     = MFMA16(pa[f0],                       \
                            vvPV[half * 4 + fc], acc[f0][fc]);                 \
                        acc[f0 + 1][fc] = MFMA16(pa[f0 + 1],                   \
                            vvPV[half * 4 + fc], acc[f0 + 1][fc]);             \
                    }                                                          \
                }                                                              \
            }                                                                  \
        }                                                                      \
        /* exp(IT) -> P-buf KC, accumulate denominator */                      \
        {                                                                      \
            bf16* Pc = Pb + (size_t)(KC) * (64 * 72);                          \
            _Pragma("unroll")                                                  \
            for (int i = 0; i < 4; ++i) {                                      \
                const int row = qrb + lg * 4 + i;                              \
                float p0 = __builtin_amdgcn_exp2f(s0[i] * scale2);             \
                float p1 = __builtin_amdgcn_exp2f(s1[i] * scale2);             \
                Pc[row * 72 + par * 32 + lc]      = (bf16)p0;                  \
                Pc[row * 72 + par * 32 + 16 + lc] = (bf16)p1;                  \
                Lacc[i] += p0 + p1;                                            \
            }                                                                  \
        }                                                                      \
        /* K(IT+1) landed (oldest); P(IT) visible; V(IT) may still fly */      \
        asm volatile("s_waitcnt vmcnt(8) lgkmcnt(0)" ::: "memory");            \
        __builtin_amdgcn_s_barrier();                                          \
    }

    // iter 0: no PV yet; loads V(0) into vvA
    ITER_BODY(0, 0, vvA, vvB, false, true)

    // iters 1..62 (31 double-iterations); odd loads vvB/uses vvA, even swaps
    for (int t2 = 0; t2 < 31; ++t2) {
        const int i = 2 * t2 + 1;
        ITER_BODY(i,     1, vvB, vvA, true, true)
        ITER_BODY(i + 1, 0, vvA, vvB, true, true)
    }

    // iter 63: odd (KC=1), no prefetch; loads V(63) into vvB, PV(62) from vvA
    ITER_BODY(63, 1, vvB, vvA, true, false)

    // final PV(63): P from Pb[1], V from vvB
    {
        const bf16* Pp = Pb + (size_t)1 * (64 * 72);
#pragma unroll
        for (int kk2 = 0; kk2 < 2; ++kk2) {
            bf16x8 pa[4];
#pragma unroll
            for (int fr = 0; fr < 4; ++fr)
                pa[fr] = *(const bf16x8*)&Pp[(fr * 16 + lc) * 72 + kk2 * 32 + lg * 8];
#pragma unroll
            for (int fc = 0; fc < 4; ++fc)
#pragma unroll
                for (int fr = 0; fr < 4; ++fr)
                    acc[fr][fc] = MFMA16(pa[fr], vvB[kk2 * 4 + fc], acc[fr][fc]);
        }
    }
#undef ITER_BODY

    // ---- denominator: reduce per-lane partials across the 16 lc lanes ----
#pragma unroll
    for (int d = 1; d < 16; d <<= 1)
#pragma unroll
        for (int i = 0; i < 4; ++i)
            Lacc[i] += __shfl_xor(Lacc[i], d);
    if (lc == 0)
#pragma unroll
        for (int i = 0; i < 4; ++i)
            l_part[qrb + lg * 4 + i][par] = Lacc[i];
    __syncthreads();

    // ---- epilogue: divide by denominator, store fp32 ----
    for (int fr = 0; fr < 4; ++fr) {
        float invl[4];
#pragma unroll
        for (int i = 0; i < 4; ++i) {
            const int row = fr * 16 + lg * 4 + i;
            invl[i] = 1.0f / (l_part[row][0] + l_part[row][1]);
        }
        for (int fc = 0; fc < 4; ++fc) {
            const size_t base =
                ((size_t)(b * 4096 + q0 + fr * 16 + lg * 4)) * 512 + w * 64 + fc * 16 + lc;
#pragma unroll
            for (int i = 0; i < 4; ++i)
                Out[base + (size_t)i * 512] = acc[fr][fc][i] * invl[i];
        }
    }
}

// ---------------------------------------------------------------------------
extern "C" void kernel_launch(void* const* d_in, const int* in_sizes, int n_in,
                              void* d_out, int out_size, void* d_ws, size_t ws_size,
                              hipStream_t stream) {
    const float* X    = (const float*)d_in[0];
    const float* Wq   = (const float*)d_in[1];
    const float* Wk   = (const float*)d_in[2];
    const float* Wv   = (const float*)d_in[3];
    const float* temp = (const float*)d_in[4];
    float* Out = (float*)d_out;

    const size_t NE = (size_t)4 * 4096 * 512;
    bf16* Qw = (bf16*)d_ws;
    bf16* Kw = Qw + NE;
    bf16* Vt = Kw + NE;

    proj_kernel<<<dim3(128, 4, 3), 256, 0, stream>>>(X, Wq, Wk, Wv, Qw, Kw, Vt);

    // dynamic LDS: 2 K-buffers (128 KiB) + 2 P-buffers (18 KiB) = 149504 B
    const size_t smem_bytes = (size_t)2 * 64 * 512 * 2 + (size_t)2 * 64 * 72 * 2;
    flash_kernel<<<dim3(256), 512, smem_bytes, stream>>>(Qw, Kw, Vt, temp, Out);
}